// Round 4
// baseline (3945.503 us; speedup 1.0000x reference)
//
#include <hip/hip_runtime.h>
#include <math.h>

#define N_NODES 4000
#define CC 191
#define CP 192
#define NT 3
#define NB 5
#define NS 10
#define EE 12000
#define GG 32
#define THREE_C 573
#define NC (N_NODES * CP)
#define NPAD 576          // padded gate-row count (573 -> 576)

typedef __attribute__((ext_vector_type(8))) short short8;
typedef __attribute__((ext_vector_type(4))) float f32x4;

__device__ __forceinline__ unsigned short f2bf(float f) {
    unsigned u = __float_as_uint(f);
    unsigned r = (u + 0x7fffu + ((u >> 16) & 1u)) >> 16;
    return (unsigned short)r;
}
__device__ __forceinline__ float bf2f(unsigned short s) {
    return __uint_as_float(((unsigned)s) << 16);
}
__device__ __forceinline__ float dot4(float4 a, float4 b) {
    return a.x * b.x + a.y * b.y + a.z * b.z + a.w * b.w;
}

// ---------------------------------------------------------------- build h
__global__ void k_build_h(const float* __restrict__ xs, const int* __restrict__ xtype,
                          const int* __restrict__ xtok, float* __restrict__ h) {
    int idx = blockIdx.x * 256 + threadIdx.x;
    if (idx >= NC) return;
    int i = idx / CP, c = idx % CP;
    float v = 0.f;
    if (c < 60) {
        v = (xtype[i] == c) ? 1.f : 0.f;
    } else if (c < 189) {
        int tk = xtok[i];
        tk = tk < 0 ? 0 : (tk > 128 ? 128 : tk);
        v = (tk == c - 60) ? 1.f : 0.f;
    } else if (c < CC) {
        v = xs[i * 2 + (c - 189)];
    }
    h[idx] = v;
}

// ------------------------------------------------- pad conv_w -> [150][192][192]
__global__ void k_pad_conv(const float* __restrict__ w, float* __restrict__ wp) {
    long idx = (long)blockIdx.x * 256 + threadIdx.x;
    if (idx >= 150L * 192 * 192) return;
    int b = (int)(idx / (192 * 192));
    int r = (int)((idx / 192) % 192);
    int c = (int)(idx % 192);
    wp[idx] = (r < CC && c < CC) ? w[(long)b * CC * CC + (long)r * CC + c] : 0.f;
}

// ---------------------------------- pad [batches][573][191] -> [batches][573][192]
__global__ void k_pad573(const float* __restrict__ w, float* __restrict__ wp, int batches) {
    long tot = (long)batches * THREE_C * CP;
    long idx = (long)blockIdx.x * 256 + threadIdx.x;
    if (idx >= tot) return;
    int b = (int)(idx / (THREE_C * CP));
    int r = (int)((idx / CP) % THREE_C);
    int c = (int)(idx % CP);
    wp[idx] = (c < CC) ? w[((long)b * THREE_C + r) * CC + c] : 0.f;
}

// --------------------------------------------------------------- CSR build
__global__ void k_edge_count(const int* __restrict__ ei, const int* __restrict__ et,
                             int* __restrict__ cnt) {
    int e = blockIdx.x * 256 + threadIdx.x;
    if (e >= EE) return;
    atomicAdd(&cnt[et[e] * N_NODES + ei[EE + e]], 1);
}

__global__ void k_scan(const int* __restrict__ cnt, int* __restrict__ off, int* __restrict__ fill) {
    const int TOT = NT * N_NODES;
    const int CH = (TOT + 255) / 256;
    __shared__ int ls[256];
    int tid = threadIdx.x;
    int base = tid * CH;
    int s = 0;
    for (int u = 0; u < CH; u++) {
        int idx = base + u;
        if (idx < TOT) s += cnt[idx];
    }
    ls[tid] = s;
    __syncthreads();
    for (int d = 1; d < 256; d <<= 1) {
        int v = 0;
        if (tid >= d) v = ls[tid - d];
        __syncthreads();
        if (tid >= d) ls[tid] += v;
        __syncthreads();
    }
    int run = (tid > 0) ? ls[tid - 1] : 0;
    for (int u = 0; u < CH; u++) {
        int idx = base + u;
        if (idx < TOT) {
            off[idx] = run;
            fill[idx] = run;
            run += cnt[idx];
        }
    }
    if (tid == 255) off[TOT] = run;
}

__global__ void k_edge_fill(const int* __restrict__ ei, const int* __restrict__ et,
                            int* __restrict__ fill, int* __restrict__ csrc) {
    int e = blockIdx.x * 256 + threadIdx.x;
    if (e >= EE) return;
    int pos = atomicAdd(&fill[et[e] * N_NODES + ei[EE + e]], 1);
    csrc[pos] = ei[e];
}

// ------------------------------------ F_t[ts][j3][k] = sum_q wih[j3][q]*conv[ts][k][q]
__global__ __launch_bounds__(256) void k_fmat(const float* __restrict__ wih_p,
                                              const float* __restrict__ conv_wp,
                                              float* __restrict__ F_t, int b) {
    int ts = blockIdx.z;
    int t = ts / NS;
    int j30 = blockIdx.x * 32;
    int k0 = blockIdx.y * 64;
    const float* A = wih_p + (long)(b * 3 + t) * THREE_C * CP;
    const float* B = conv_wp + ((long)b * 30 + ts) * 192 * 192;
    __shared__ float sA[32 * 52];
    __shared__ float sB[64 * 52];
    int tid = threadIdx.x;
    int tj = tid % 32;
    int tn = tid / 32;
    float acc0[4] = {0, 0, 0, 0}, acc1[4] = {0, 0, 0, 0};
    for (int kb = 0; kb < 4; kb++) {
        int q0 = kb * 48;
        for (int idx = tid; idx < 32 * 12; idx += 256) {
            int row = idx / 12, c4 = idx % 12;
            int j3 = j30 + row; j3 = j3 < THREE_C ? j3 : THREE_C - 1;
            *(float4*)(sA + row * 52 + c4 * 4) = *(const float4*)(A + (long)j3 * CP + q0 + c4 * 4);
        }
        for (int idx = tid; idx < 64 * 12; idx += 256) {
            int row = idx / 12, c4 = idx % 12;
            *(float4*)(sB + row * 52 + c4 * 4) = *(const float4*)(B + (long)(k0 + row) * CP + q0 + c4 * 4);
        }
        __syncthreads();
        #pragma unroll 3
        for (int q4 = 0; q4 < 12; q4++) {
            float4 bv0 = *(const float4*)(sB + tj * 52 + q4 * 4);
            float4 bv1 = *(const float4*)(sB + (tj + 32) * 52 + q4 * 4);
            #pragma unroll
            for (int u = 0; u < 4; u++) {
                float4 av = *(const float4*)(sA + (tn + 8 * u) * 52 + q4 * 4);
                acc0[u] += dot4(av, bv0);
                acc1[u] += dot4(av, bv1);
            }
        }
        __syncthreads();
    }
    #pragma unroll
    for (int u = 0; u < 4; u++) {
        int j3 = j30 + tn + 8 * u;
        if (j3 < THREE_C) {
            F_t[((long)ts * THREE_C + j3) * CP + k0 + tj] = acc0[u];
            F_t[((long)ts * THREE_C + j3) * CP + k0 + tj + 32] = acc1[u];
        }
    }
}

// ------------------- convert F_t fp32 -> FH/FL bf16 [30][576][192], rows permuted p=3j+g
__global__ void k_convF(const float* __restrict__ F_t, unsigned short* __restrict__ FH,
                        unsigned short* __restrict__ FL) {
    long idx = (long)blockIdx.x * 256 + threadIdx.x;
    if (idx >= 30L * NPAD * CP) return;
    int k = (int)(idx % CP);
    int p = (int)((idx / CP) % NPAD);
    int ts = (int)(idx / ((long)NPAD * CP));
    float v = 0.f;
    if (p < THREE_C) {
        int j = p / 3, g = p % 3;
        v = F_t[((long)ts * THREE_C + g * CC + j) * CP + k];
    }
    unsigned short hi = f2bf(v);
    FH[idx] = hi;
    FL[idx] = f2bf(v - bf2f(hi));
}

// ------------------- convert whh_p fp32 -> WH/WL bf16 [3][576][192], rows permuted
__global__ void k_convW(const float* __restrict__ whh_p, unsigned short* __restrict__ WH,
                        unsigned short* __restrict__ WL, int b) {
    long idx = (long)blockIdx.x * 256 + threadIdx.x;
    if (idx >= 3L * NPAD * CP) return;
    int k = (int)(idx % CP);
    int p = (int)((idx / CP) % NPAD);
    int t = (int)(idx / ((long)NPAD * CP));
    float v = 0.f;
    if (p < THREE_C) {
        int j = p / 3, g = p % 3;
        v = whh_p[((long)(b * 3 + t) * THREE_C + g * CC + j) * CP + k];
    }
    unsigned short hi = f2bf(v);
    WH[idx] = hi;
    WL[idx] = f2bf(v - bf2f(hi));
}

// ------------------- h fp32 -> X0 hi/lo bf16 for the 3 type-chains
__global__ void k_split3(const float* __restrict__ h, unsigned short* __restrict__ XH,
                         unsigned short* __restrict__ XL) {
    int idx = blockIdx.x * 256 + threadIdx.x;
    if (idx >= NC) return;
    float f = h[idx];
    unsigned short hi = f2bf(f);
    unsigned short lo = f2bf(f - bf2f(hi));
    #pragma unroll
    for (int t = 0; t < NT; t++) {
        XH[(long)t * NC + idx] = hi;
        XL[(long)t * NC + idx] = lo;
    }
}

// ------------------- Agg hi/lo from X hi/lo via CSR gather
__global__ void k_agg(const unsigned short* __restrict__ XH, const unsigned short* __restrict__ XL,
                      unsigned short* __restrict__ AH, unsigned short* __restrict__ AL,
                      const int* __restrict__ off, const int* __restrict__ csrc) {
    int node = blockIdx.x;
    int t = blockIdx.y;
    int k = threadIdx.x;   // 192
    const unsigned short* Xh = XH + (long)t * NC;
    const unsigned short* Xl = XL + (long)t * NC;
    int e0 = off[t * N_NODES + node];
    int e1 = off[t * N_NODES + node + 1];
    float s = 0.f;
    for (int e = e0; e < e1; e++) {
        long base = (long)csrc[e] * CP + k;
        s += bf2f(Xh[base]) + bf2f(Xl[base]);
    }
    unsigned short hi = f2bf(s);
    long o = ((long)t * N_NODES + node) * CP + k;
    AH[o] = hi;
    AL[o] = f2bf(s - bf2f(hi));
}

// =================== hot kernel: dual MFMA GEMM (GI, GH) + fused GRU epilogue
// tile 128M x 96N, K=192 in 6 super-stages; compensated bf16: Ah*Bh + Al*Bh + Ah*Bl.
// LDS layout XOR-swizzled: slot(row,q) = row*4 + (q ^ ((row>>1)&3)), 16B slots.
__global__ __launch_bounds__(256, 2) void k_step(
        const unsigned short* __restrict__ XcH, const unsigned short* __restrict__ XcL,
        const unsigned short* __restrict__ AgH, const unsigned short* __restrict__ AgL,
        const unsigned short* __restrict__ FH, const unsigned short* __restrict__ FL,
        const unsigned short* __restrict__ WH, const unsigned short* __restrict__ WL,
        const float* __restrict__ bih, const float* __restrict__ bhh,
        unsigned short* __restrict__ XnH, unsigned short* __restrict__ XnL,
        int b, int s) {
    const int t = blockIdx.z;
    const int ts = t * NS + s;
    const int M0 = blockIdx.x * 128;
    const int N0 = blockIdx.y * 96;

    // 56 KB: XH 0, GH 4096, XL 8192, GL 12288 (halfword offsets; 128 rows x 32 half)
    //        FH 16384, WH 19456, FL 22528, WL 25600 (96 rows x 32 half)
    __shared__ __align__(16) unsigned short smem[28672];

    const int tid = threadIdx.x;
    const int lane = tid & 63;
    const int wave = tid >> 6;
    const int wm = wave & 1;      // M-half (64 rows)
    const int wn = wave >> 1;     // N-half (48 rows)
    const int l15 = lane & 15;
    const int kb = lane >> 4;

    const unsigned short* gA[4];
    gA[0] = XcH + (size_t)t * NC;
    gA[1] = AgH + (size_t)t * NC;
    gA[2] = XcL + (size_t)t * NC;
    gA[3] = AgL + (size_t)t * NC;
    const unsigned short* gB[4];
    gB[0] = FH + (size_t)ts * NPAD * CP;
    gB[1] = WH + (size_t)t * NPAD * CP;
    gB[2] = FL + (size_t)ts * NPAD * CP;
    gB[3] = WL + (size_t)t * NPAD * CP;

    f32x4 accGI[4][3], accGH[4][3];
    #pragma unroll
    for (int mi = 0; mi < 4; mi++)
        #pragma unroll
        for (int nj = 0; nj < 3; nj++) {
            accGI[mi][nj] = (f32x4){0.f, 0.f, 0.f, 0.f};
            accGH[mi][nj] = (f32x4){0.f, 0.f, 0.f, 0.f};
        }

    for (int k = 0; k < 6; k++) {
        const int ko = k * 32;
        __syncthreads();   // protect previous stage's LDS from overwrite
        // ---- stage A: 4 arrays x 128 rows x 32 half (2048 slots of 16B)
        #pragma unroll
        for (int i = 0; i < 8; i++) {
            int c = tid + i * 256;
            int a = c >> 9;
            int r = (c >> 2) & 127;
            int qs = c & 3;
            int q = qs ^ ((r >> 1) & 3);
            int node = M0 + r; node = node < N_NODES ? node : N_NODES - 1;
            const unsigned short* gp = gA[a] + (size_t)node * CP + ko + q * 8;
            *(uint4*)(smem + a * 4096 + (r * 4 + qs) * 8) = *(const uint4*)gp;
        }
        // ---- stage B: 4 arrays x 96 rows x 32 half (1536 slots)
        #pragma unroll
        for (int i = 0; i < 6; i++) {
            int c = tid + i * 256;
            int a = c / 384;
            int rem = c - a * 384;
            int r = rem >> 2;
            int qs = rem & 3;
            int q = qs ^ ((r >> 1) & 3);
            const unsigned short* gp = gB[a] + (size_t)(N0 + r) * CP + ko + q * 8;
            *(uint4*)(smem + 16384 + a * 3072 + (r * 4 + qs) * 8) = *(const uint4*)gp;
        }
        __syncthreads();

        short8 xh[4], gh[4], xl[4], gl[4];
        #pragma unroll
        for (int mi = 0; mi < 4; mi++) {
            int r = wm * 64 + mi * 16 + l15;
            int sl = (r * 4 + (kb ^ ((r >> 1) & 3))) * 8;
            xh[mi] = *(const short8*)(smem + sl);
            gh[mi] = *(const short8*)(smem + 4096 + sl);
            xl[mi] = *(const short8*)(smem + 8192 + sl);
            gl[mi] = *(const short8*)(smem + 12288 + sl);
        }
        short8 fh[3], wh[3], fl[3], wl[3];
        #pragma unroll
        for (int nj = 0; nj < 3; nj++) {
            int r = wn * 48 + nj * 16 + l15;
            int sl = (r * 4 + (kb ^ ((r >> 1) & 3))) * 8;
            fh[nj] = *(const short8*)(smem + 16384 + sl);
            wh[nj] = *(const short8*)(smem + 19456 + sl);
            fl[nj] = *(const short8*)(smem + 22528 + sl);
            wl[nj] = *(const short8*)(smem + 25600 + sl);
        }
        #pragma unroll
        for (int mi = 0; mi < 4; mi++)
            #pragma unroll
            for (int nj = 0; nj < 3; nj++) {
                accGI[mi][nj] = __builtin_amdgcn_mfma_f32_16x16x32_bf16(
                    gh[mi], fh[nj], accGI[mi][nj], 0, 0, 0);
                accGI[mi][nj] = __builtin_amdgcn_mfma_f32_16x16x32_bf16(
                    gl[mi], fh[nj], accGI[mi][nj], 0, 0, 0);
                accGI[mi][nj] = __builtin_amdgcn_mfma_f32_16x16x32_bf16(
                    gh[mi], fl[nj], accGI[mi][nj], 0, 0, 0);
                accGH[mi][nj] = __builtin_amdgcn_mfma_f32_16x16x32_bf16(
                    xh[mi], wh[nj], accGH[mi][nj], 0, 0, 0);
                accGH[mi][nj] = __builtin_amdgcn_mfma_f32_16x16x32_bf16(
                    xl[mi], wh[nj], accGH[mi][nj], 0, 0, 0);
                accGH[mi][nj] = __builtin_amdgcn_mfma_f32_16x16x32_bf16(
                    xh[mi], wl[nj], accGH[mi][nj], 0, 0, 0);
            }
    }

    // ---------------- GRU epilogue: 4 phases, one wave's 64x48 quadrant each
    float* eGI = (float*)smem;           // 64 x 50
    float* eGH = eGI + 3200;             // 64 x 50
    const int c = tid & 15;              // channel within 16
    const int rg = tid >> 4;             // row group (0..15)
    const int bo = (b * 3 + t) * THREE_C;

    for (int p = 0; p < 4; p++) {
        __syncthreads();
        if (wave == p) {
            #pragma unroll
            for (int mi = 0; mi < 4; mi++)
                #pragma unroll
                for (int nj = 0; nj < 3; nj++)
                    #pragma unroll
                    for (int r = 0; r < 4; r++) {
                        int grow = mi * 16 + kb * 4 + r;
                        int gcol = nj * 16 + l15;
                        eGI[grow * 50 + gcol] = accGI[mi][nj][r];
                        eGH[grow * 50 + gcol] = accGH[mi][nj][r];
                    }
        }
        __syncthreads();
        int pm = p & 1, pn = p >> 1;
        int j = blockIdx.y * 32 + pn * 16 + c;   // absolute channel
        float bir = 0, biz = 0, bic = 0, bhr = 0, bhz = 0, bhc = 0;
        if (j < CC) {
            bir = bih[bo + j]; biz = bih[bo + CC + j]; bic = bih[bo + 2 * CC + j];
            bhr = bhh[bo + j]; bhz = bhh[bo + CC + j]; bhc = bhh[bo + 2 * CC + j];
        }
        #pragma unroll
        for (int q = 0; q < 4; q++) {
            int lr = rg * 4 + q;
            int node = M0 + pm * 64 + lr;
            if (node >= N_NODES) continue;
            unsigned short oh = 0, ol = 0;
            if (j < CC) {
                float gir = eGI[lr * 50 + 3 * c], giz = eGI[lr * 50 + 3 * c + 1],
                      gic = eGI[lr * 50 + 3 * c + 2];
                float ghr = eGH[lr * 50 + 3 * c], ghz = eGH[lr * 50 + 3 * c + 1],
                      ghc = eGH[lr * 50 + 3 * c + 2];
                size_t xi = (size_t)(t * N_NODES + node) * CP + j;
                float xold = bf2f(XcH[xi]) + bf2f(XcL[xi]);
                float rr = 1.f / (1.f + expf(-(gir + bir + ghr + bhr)));
                float zz = 1.f / (1.f + expf(-(giz + biz + ghz + bhz)));
                float cg = tanhf(gic + bic + rr * (ghc + bhc));
                float outv = (1.f - zz) * cg + zz * xold;
                oh = f2bf(outv);
                ol = f2bf(outv - bf2f(oh));
            }
            size_t oi = (size_t)(t * N_NODES + node) * CP + j;
            XnH[oi] = oh;
            XnL[oi] = ol;
        }
    }
}

// --------------------------------------------------------- LayerNorm + ReLU
__global__ void k_ln(float* __restrict__ h, const unsigned short* __restrict__ XH,
                     const unsigned short* __restrict__ XL,
                     const float* __restrict__ lnw, const float* __restrict__ lnb, int b) {
    int i = blockIdx.x;
    int c = threadIdx.x;   // 192 threads
    long base = (long)i * CP + c;
    float v = 0.f;
    if (c < CC) {
        v = h[base];
        #pragma unroll
        for (int t = 0; t < NT; t++)
            v += bf2f(XH[(long)t * NC + base]) + bf2f(XL[(long)t * NC + base]);
    }
    float sv = v;
    for (int o = 32; o > 0; o >>= 1) sv += __shfl_down(sv, o);
    __shared__ float ls[3];
    __shared__ float bc[2];
    if ((threadIdx.x & 63) == 0) ls[threadIdx.x >> 6] = sv;
    __syncthreads();
    if (threadIdx.x == 0) bc[0] = (ls[0] + ls[1] + ls[2]) / (float)CC;
    __syncthreads();
    float mu = bc[0];
    float d = (c < CC) ? (v - mu) : 0.f;
    float s2 = d * d;
    for (int o = 32; o > 0; o >>= 1) s2 += __shfl_down(s2, o);
    __syncthreads();
    if ((threadIdx.x & 63) == 0) ls[threadIdx.x >> 6] = s2;
    __syncthreads();
    if (threadIdx.x == 0) bc[1] = (ls[0] + ls[1] + ls[2]) / (float)CC;
    __syncthreads();
    float var = bc[1];
    float y = 0.f;
    if (c < CC) {
        y = d * rsqrtf(var + 1e-5f) * lnw[b * CC + c] + lnb[b * CC + c];
        y = y > 0.f ? y : 0.f;
    }
    h[base] = y;
}

// --------------------------------------------------------------- pooling
__global__ void k_pool(const float* __restrict__ h, const int* __restrict__ batch,
                       float* __restrict__ hg, float* __restrict__ gcnt) {
    int idx = blockIdx.x * 256 + threadIdx.x;
    if (idx >= NC) return;
    int i = idx / CP, c = idx % CP;
    int g = batch[i];
    if (c < CC) atomicAdd(&hg[g * CP + c], h[idx]);
    if (c == 0) atomicAdd(&gcnt[g], 1.f);
}

__global__ void k_head1(const float* __restrict__ hg, const float* __restrict__ gcnt,
                        const float* __restrict__ w1, const float* __restrict__ b1,
                        float* __restrict__ z1) {
    int g = blockIdx.x;
    int jcol = threadIdx.x;
    if (jcol >= CC) return;
    float inv = 1.f / fmaxf(gcnt[g], 1.f);
    float acc = 0.f;
    for (int k = 0; k < CC; k++) acc += hg[g * CP + k] * inv * w1[k * CC + jcol];
    acc += b1[jcol];
    z1[g * CP + jcol] = fmaxf(acc, 0.f);
}

__global__ void k_head2(const float* __restrict__ z1, const float* __restrict__ w2,
                        const float* __restrict__ b2, float* __restrict__ out) {
    int idx = threadIdx.x;
    if (idx >= GG * 2) return;
    int g = idx / 2, o = idx % 2;
    float acc = 0.f;
    for (int k = 0; k < CC; k++) acc += z1[g * CP + k] * w2[k * 2 + o];
    out[g * 2 + o] = acc + b2[o];
}

// ================================================================ launch
extern "C" void kernel_launch(void* const* d_in, const int* in_sizes, int n_in,
                              void* d_out, int out_size, void* d_ws, size_t ws_size,
                              hipStream_t stream) {
    const float* xs   = (const float*)d_in[0];
    const float* conv = (const float*)d_in[1];
    const float* wih  = (const float*)d_in[2];
    const float* whh  = (const float*)d_in[3];
    const float* bih  = (const float*)d_in[4];
    const float* bhh  = (const float*)d_in[5];
    const float* lnw  = (const float*)d_in[6];
    const float* lnb  = (const float*)d_in[7];
    const float* hw1  = (const float*)d_in[8];
    const float* hb1  = (const float*)d_in[9];
    const float* hw2  = (const float*)d_in[10];
    const float* hb2  = (const float*)d_in[11];
    const int* xtype  = (const int*)d_in[12];
    const int* xtok   = (const int*)d_in[13];
    const int* ei     = (const int*)d_in[14];
    const int* et     = (const int*)d_in[15];
    const int* batch  = (const int*)d_in[16];
    float* out = (float*)d_out;

    char* ws = (char*)d_ws;
    size_t o = 0;
    auto alloc = [&](size_t nbytes) {
        size_t r = o;
        o = (o + nbytes + 255) & ~(size_t)255;
        return r;
    };
    float* h      = (float*)(ws + alloc((size_t)NC * 4));
    float* F_t    = (float*)(ws + alloc((size_t)30 * THREE_C * CP * 4));
    float* wih_p  = (float*)(ws + alloc((size_t)15 * THREE_C * CP * 4));
    float* whh_p  = (float*)(ws + alloc((size_t)15 * THREE_C * CP * 4));
    float* convp  = (float*)(ws + alloc((size_t)150 * 192 * 192 * 4));
    unsigned short* FH  = (unsigned short*)(ws + alloc((size_t)30 * NPAD * CP * 2));
    unsigned short* FL  = (unsigned short*)(ws + alloc((size_t)30 * NPAD * CP * 2));
    unsigned short* WH  = (unsigned short*)(ws + alloc((size_t)3 * NPAD * CP * 2));
    unsigned short* WL  = (unsigned short*)(ws + alloc((size_t)3 * NPAD * CP * 2));
    unsigned short* XAh = (unsigned short*)(ws + alloc((size_t)NT * NC * 2));
    unsigned short* XAl = (unsigned short*)(ws + alloc((size_t)NT * NC * 2));
    unsigned short* XBh = (unsigned short*)(ws + alloc((size_t)NT * NC * 2));
    unsigned short* XBl = (unsigned short*)(ws + alloc((size_t)NT * NC * 2));
    unsigned short* AggH = (unsigned short*)(ws + alloc((size_t)NT * NC * 2));
    unsigned short* AggL = (unsigned short*)(ws + alloc((size_t)NT * NC * 2));
    float* hg     = (float*)(ws + alloc((size_t)GG * CP * 4));
    float* gcnt   = (float*)(ws + alloc((size_t)GG * 4));
    float* z1buf  = (float*)(ws + alloc((size_t)GG * CP * 4));
    int* cnt      = (int*)(ws + alloc((size_t)NT * N_NODES * 4));
    int* offb     = (int*)(ws + alloc((size_t)(NT * N_NODES + 1) * 4));
    int* fillb    = (int*)(ws + alloc((size_t)NT * N_NODES * 4));
    int* csrc     = (int*)(ws + alloc((size_t)EE * 4));
    (void)ws_size; (void)n_in; (void)in_sizes; (void)out_size;

    hipMemsetAsync(cnt, 0, (size_t)NT * N_NODES * 4, stream);
    hipMemsetAsync(hg, 0, (size_t)GG * CP * 4, stream);
    hipMemsetAsync(gcnt, 0, (size_t)GG * 4, stream);

    k_build_h<<<(NC + 255) / 256, 256, 0, stream>>>(xs, xtype, xtok, h);
    k_pad_conv<<<(int)((150L * 192 * 192 + 255) / 256), 256, 0, stream>>>(conv, convp);
    k_pad573<<<(int)(((long)15 * THREE_C * CP + 255) / 256), 256, 0, stream>>>(wih, wih_p, 15);
    k_pad573<<<(int)(((long)15 * THREE_C * CP + 255) / 256), 256, 0, stream>>>(whh, whh_p, 15);
    k_edge_count<<<(EE + 255) / 256, 256, 0, stream>>>(ei, et, cnt);
    k_scan<<<1, 256, 0, stream>>>(cnt, offb, fillb);
    k_edge_fill<<<(EE + 255) / 256, 256, 0, stream>>>(ei, et, fillb, csrc);

    for (int b = 0; b < NB; b++) {
        dim3 fg((THREE_C + 31) / 32, 3, 30);
        k_fmat<<<fg, 256, 0, stream>>>(wih_p, convp, F_t, b);
        k_convF<<<(int)((30L * NPAD * CP + 255) / 256), 256, 0, stream>>>(F_t, FH, FL);
        k_convW<<<(int)((3L * NPAD * CP + 255) / 256), 256, 0, stream>>>(whh_p, WH, WL, b);
        k_split3<<<(NC + 255) / 256, 256, 0, stream>>>(h, XAh, XAl);
        unsigned short *curH = XAh, *curL = XAl, *nxtH = XBh, *nxtL = XBl;
        for (int s = 0; s < NS; s++) {
            k_agg<<<dim3(N_NODES, NT), CP, 0, stream>>>(curH, curL, AggH, AggL, offb, csrc);
            dim3 sg(32, 6, NT);   // 4096/128 node tiles x 576/96 gate tiles x types
            k_step<<<sg, 256, 0, stream>>>(curH, curL, AggH, AggL, FH, FL, WH, WL,
                                           bih, bhh, nxtH, nxtL, b, s);
            unsigned short* t1 = curH; curH = nxtH; nxtH = t1;
            unsigned short* t2 = curL; curL = nxtL; nxtL = t2;
        }
        // NS even -> final state is back in XAh/XAl
        k_ln<<<N_NODES, CP, 0, stream>>>(h, XAh, XAl, lnw, lnb, b);
    }

    k_pool<<<(NC + 255) / 256, 256, 0, stream>>>(h, batch, hg, gcnt);
    k_head1<<<GG, CP, 0, stream>>>(hg, gcnt, hw1, hb1, z1buf);
    k_head2<<<1, 64, 0, stream>>>(z1buf, hw2, hb2, out);
}

// Round 5
// 2745.512 us; speedup vs baseline: 1.4371x; 1.4371x over previous
//
#include <hip/hip_runtime.h>
#include <math.h>

#define N_NODES 4000
#define CC 191
#define CP 192
#define NT 3
#define NB 5
#define NS 10
#define EE 12000
#define GG 32
#define THREE_C 573
#define NC (N_NODES * CP)
#define NPAD 576          // padded gate-row count (573 -> 576)

typedef __attribute__((ext_vector_type(8))) short short8;
typedef __attribute__((ext_vector_type(4))) float f32x4;

__device__ __forceinline__ unsigned short f2bf(float f) {
    unsigned u = __float_as_uint(f);
    unsigned r = (u + 0x7fffu + ((u >> 16) & 1u)) >> 16;
    return (unsigned short)r;
}
__device__ __forceinline__ float bf2f(unsigned short s) {
    return __uint_as_float(((unsigned)s) << 16);
}
__device__ __forceinline__ float dot4(float4 a, float4 b) {
    return a.x * b.x + a.y * b.y + a.z * b.z + a.w * b.w;
}
// async global->LDS DMA, 16B per lane; lds dest = wave-uniform base + lane*16
__device__ __forceinline__ void dma16(const void* g, void* l) {
    __builtin_amdgcn_global_load_lds(
        (const __attribute__((address_space(1))) unsigned int*)g,
        (__attribute__((address_space(3))) unsigned int*)l, 16, 0, 0);
}

// ---------------------------------------------------------------- build h
__global__ void k_build_h(const float* __restrict__ xs, const int* __restrict__ xtype,
                          const int* __restrict__ xtok, float* __restrict__ h) {
    int idx = blockIdx.x * 256 + threadIdx.x;
    if (idx >= NC) return;
    int i = idx / CP, c = idx % CP;
    float v = 0.f;
    if (c < 60) {
        v = (xtype[i] == c) ? 1.f : 0.f;
    } else if (c < 189) {
        int tk = xtok[i];
        tk = tk < 0 ? 0 : (tk > 128 ? 128 : tk);
        v = (tk == c - 60) ? 1.f : 0.f;
    } else if (c < CC) {
        v = xs[i * 2 + (c - 189)];
    }
    h[idx] = v;
}

// ------------------------------------------------- pad conv_w -> [150][192][192]
__global__ void k_pad_conv(const float* __restrict__ w, float* __restrict__ wp) {
    long idx = (long)blockIdx.x * 256 + threadIdx.x;
    if (idx >= 150L * 192 * 192) return;
    int b = (int)(idx / (192 * 192));
    int r = (int)((idx / 192) % 192);
    int c = (int)(idx % 192);
    wp[idx] = (r < CC && c < CC) ? w[(long)b * CC * CC + (long)r * CC + c] : 0.f;
}

// ---------------------------------- pad [batches][573][191] -> [batches][573][192]
__global__ void k_pad573(const float* __restrict__ w, float* __restrict__ wp, int batches) {
    long tot = (long)batches * THREE_C * CP;
    long idx = (long)blockIdx.x * 256 + threadIdx.x;
    if (idx >= tot) return;
    int b = (int)(idx / (THREE_C * CP));
    int r = (int)((idx / CP) % THREE_C);
    int c = (int)(idx % CP);
    wp[idx] = (c < CC) ? w[((long)b * THREE_C + r) * CC + c] : 0.f;
}

// --------------------------------------------------------------- CSR build
__global__ void k_edge_count(const int* __restrict__ ei, const int* __restrict__ et,
                             int* __restrict__ cnt) {
    int e = blockIdx.x * 256 + threadIdx.x;
    if (e >= EE) return;
    atomicAdd(&cnt[et[e] * N_NODES + ei[EE + e]], 1);
}

__global__ void k_scan(const int* __restrict__ cnt, int* __restrict__ off, int* __restrict__ fill) {
    const int TOT = NT * N_NODES;
    const int CH = (TOT + 255) / 256;
    __shared__ int ls[256];
    int tid = threadIdx.x;
    int base = tid * CH;
    int s = 0;
    for (int u = 0; u < CH; u++) {
        int idx = base + u;
        if (idx < TOT) s += cnt[idx];
    }
    ls[tid] = s;
    __syncthreads();
    for (int d = 1; d < 256; d <<= 1) {
        int v = 0;
        if (tid >= d) v = ls[tid - d];
        __syncthreads();
        if (tid >= d) ls[tid] += v;
        __syncthreads();
    }
    int run = (tid > 0) ? ls[tid - 1] : 0;
    for (int u = 0; u < CH; u++) {
        int idx = base + u;
        if (idx < TOT) {
            off[idx] = run;
            fill[idx] = run;
            run += cnt[idx];
        }
    }
    if (tid == 255) off[TOT] = run;
}

__global__ void k_edge_fill(const int* __restrict__ ei, const int* __restrict__ et,
                            int* __restrict__ fill, int* __restrict__ csrc) {
    int e = blockIdx.x * 256 + threadIdx.x;
    if (e >= EE) return;
    int pos = atomicAdd(&fill[et[e] * N_NODES + ei[EE + e]], 1);
    csrc[pos] = ei[e];
}

// ------------------------------------ F_t[ts][j3][k] = sum_q wih[j3][q]*conv[ts][k][q]
__global__ __launch_bounds__(256) void k_fmat(const float* __restrict__ wih_p,
                                              const float* __restrict__ conv_wp,
                                              float* __restrict__ F_t, int b) {
    int ts = blockIdx.z;
    int t = ts / NS;
    int j30 = blockIdx.x * 32;
    int k0 = blockIdx.y * 64;
    const float* A = wih_p + (long)(b * 3 + t) * THREE_C * CP;
    const float* B = conv_wp + ((long)b * 30 + ts) * 192 * 192;
    __shared__ float sA[32 * 52];
    __shared__ float sB[64 * 52];
    int tid = threadIdx.x;
    int tj = tid % 32;
    int tn = tid / 32;
    float acc0[4] = {0, 0, 0, 0}, acc1[4] = {0, 0, 0, 0};
    for (int kb = 0; kb < 4; kb++) {
        int q0 = kb * 48;
        for (int idx = tid; idx < 32 * 12; idx += 256) {
            int row = idx / 12, c4 = idx % 12;
            int j3 = j30 + row; j3 = j3 < THREE_C ? j3 : THREE_C - 1;
            *(float4*)(sA + row * 52 + c4 * 4) = *(const float4*)(A + (long)j3 * CP + q0 + c4 * 4);
        }
        for (int idx = tid; idx < 64 * 12; idx += 256) {
            int row = idx / 12, c4 = idx % 12;
            *(float4*)(sB + row * 52 + c4 * 4) = *(const float4*)(B + (long)(k0 + row) * CP + q0 + c4 * 4);
        }
        __syncthreads();
        #pragma unroll 3
        for (int q4 = 0; q4 < 12; q4++) {
            float4 bv0 = *(const float4*)(sB + tj * 52 + q4 * 4);
            float4 bv1 = *(const float4*)(sB + (tj + 32) * 52 + q4 * 4);
            #pragma unroll
            for (int u = 0; u < 4; u++) {
                float4 av = *(const float4*)(sA + (tn + 8 * u) * 52 + q4 * 4);
                acc0[u] += dot4(av, bv0);
                acc1[u] += dot4(av, bv1);
            }
        }
        __syncthreads();
    }
    #pragma unroll
    for (int u = 0; u < 4; u++) {
        int j3 = j30 + tn + 8 * u;
        if (j3 < THREE_C) {
            F_t[((long)ts * THREE_C + j3) * CP + k0 + tj] = acc0[u];
            F_t[((long)ts * THREE_C + j3) * CP + k0 + tj + 32] = acc1[u];
        }
    }
}

// --- convert F_t fp32 -> FH/FL bf16 [30][576][192], epilogue-friendly permutation:
// p -> B0=p/96, v=(p%96)>>4, u=p&15 : gate=v%3, channel j=B0*32+(v/3)*16+u
__global__ void k_convF(const float* __restrict__ F_t, unsigned short* __restrict__ FH,
                        unsigned short* __restrict__ FL) {
    long idx = (long)blockIdx.x * 256 + threadIdx.x;
    if (idx >= 30L * NPAD * CP) return;
    int k = (int)(idx % CP);
    int p = (int)((idx / CP) % NPAD);
    int ts = (int)(idx / ((long)NPAD * CP));
    int B0 = p / 96, pr = p % 96;
    int v = pr >> 4, u = pr & 15;
    int g = v % 3;
    int j = B0 * 32 + (v / 3) * 16 + u;
    float val = 0.f;
    if (j < CC) val = F_t[((long)ts * THREE_C + g * CC + j) * CP + k];
    unsigned short hi = f2bf(val);
    FH[idx] = hi;
    FL[idx] = f2bf(val - bf2f(hi));
}

// --- convert whh_p fp32 -> WH/WL bf16 [3][576][192], same permutation
__global__ void k_convW(const float* __restrict__ whh_p, unsigned short* __restrict__ WH,
                        unsigned short* __restrict__ WL, int b) {
    long idx = (long)blockIdx.x * 256 + threadIdx.x;
    if (idx >= 3L * NPAD * CP) return;
    int k = (int)(idx % CP);
    int p = (int)((idx / CP) % NPAD);
    int t = (int)(idx / ((long)NPAD * CP));
    int B0 = p / 96, pr = p % 96;
    int v = pr >> 4, u = pr & 15;
    int g = v % 3;
    int j = B0 * 32 + (v / 3) * 16 + u;
    float val = 0.f;
    if (j < CC) val = whh_p[((long)(b * 3 + t) * THREE_C + g * CC + j) * CP + k];
    unsigned short hi = f2bf(val);
    WH[idx] = hi;
    WL[idx] = f2bf(val - bf2f(hi));
}

// ------------------- h fp32 -> X0 hi/lo bf16 for the 3 type-chains
__global__ void k_split3(const float* __restrict__ h, unsigned short* __restrict__ XH,
                         unsigned short* __restrict__ XL) {
    int idx = blockIdx.x * 256 + threadIdx.x;
    if (idx >= NC) return;
    float f = h[idx];
    unsigned short hi = f2bf(f);
    unsigned short lo = f2bf(f - bf2f(hi));
    #pragma unroll
    for (int t = 0; t < NT; t++) {
        XH[(long)t * NC + idx] = hi;
        XL[(long)t * NC + idx] = lo;
    }
}

// ------------------- Agg hi/lo from X hi/lo via CSR gather
__global__ void k_agg(const unsigned short* __restrict__ XH, const unsigned short* __restrict__ XL,
                      unsigned short* __restrict__ AH, unsigned short* __restrict__ AL,
                      const int* __restrict__ off, const int* __restrict__ csrc) {
    int node = blockIdx.x;
    int t = blockIdx.y;
    int k = threadIdx.x;   // 192
    const unsigned short* Xh = XH + (long)t * NC;
    const unsigned short* Xl = XL + (long)t * NC;
    int e0 = off[t * N_NODES + node];
    int e1 = off[t * N_NODES + node + 1];
    float s = 0.f;
    for (int e = e0; e < e1; e++) {
        long base = (long)csrc[e] * CP + k;
        s += bf2f(Xh[base]) + bf2f(Xl[base]);
    }
    unsigned short hi = f2bf(s);
    long o = ((long)t * N_NODES + node) * CP + k;
    AH[o] = hi;
    AL[o] = f2bf(s - bf2f(hi));
}

// =================== hot kernel: dual MFMA GEMM (GI, GH) + register GRU epilogue
// tile 128M x 96N, K=192 in 6 stages of 32; compensated bf16: Ah*Bh + Al*Bh + Ah*Bl.
// Staging via global_load_lds DMA (lds dest linear-in-lane; XOR swizzle on source q).
// B rows pre-permuted so wave wn's 3 nj-tiles = gates {r,z,c} of channels
// [blockIdx.y*32 + wn*16, +16) -> GRU is register-only per lane.
__global__ __launch_bounds__(256, 2) void k_step(
        const unsigned short* __restrict__ XcH, const unsigned short* __restrict__ XcL,
        const unsigned short* __restrict__ AgH, const unsigned short* __restrict__ AgL,
        const unsigned short* __restrict__ FH, const unsigned short* __restrict__ FL,
        const unsigned short* __restrict__ WH, const unsigned short* __restrict__ WL,
        const float* __restrict__ bih, const float* __restrict__ bhh,
        unsigned short* __restrict__ XnH, unsigned short* __restrict__ XnL,
        int b, int s) {
    const int t = blockIdx.z;
    const int ts = t * NS + s;
    const int M0 = blockIdx.x * 128;
    const int N0 = blockIdx.y * 96;

    // byte layout: A arrays (XH,GH,XL,GL) @ a*8192, 128 rows x 4 slots x 16B
    //              B arrays (FH,WH,FL,WL) @ 32768 + a*6144, 96 rows x 4 slots x 16B
    __shared__ __align__(16) char smem[57344];

    const int tid = threadIdx.x;
    const int lane = tid & 63;
    const int wave = tid >> 6;
    const int wm = wave & 1;      // M-half (64 rows)
    const int wn = wave >> 1;     // N-half (48 rows)
    const int l15 = lane & 15;
    const int kb = lane >> 4;
    const int quad = lane >> 4;

    const unsigned short* gA[4];
    gA[0] = XcH + (size_t)t * NC;
    gA[1] = AgH + (size_t)t * NC;
    gA[2] = XcL + (size_t)t * NC;
    gA[3] = AgL + (size_t)t * NC;
    const unsigned short* gB[4];
    gB[0] = FH + (size_t)ts * NPAD * CP;
    gB[1] = WH + (size_t)t * NPAD * CP;
    gB[2] = FL + (size_t)ts * NPAD * CP;
    gB[3] = WL + (size_t)t * NPAD * CP;

    f32x4 accGI[4][3], accGH[4][3];
    #pragma unroll
    for (int mi = 0; mi < 4; mi++)
        #pragma unroll
        for (int nj = 0; nj < 3; nj++) {
            accGI[mi][nj] = (f32x4){0.f, 0.f, 0.f, 0.f};
            accGH[mi][nj] = (f32x4){0.f, 0.f, 0.f, 0.f};
        }

    const int ldso = (tid & 192) << 4;   // wave slot base * 16B
    // per-thread invariant source pieces
    const int qsA = tid & 3;
    const int rA_lo = tid >> 2;          // 0..63

    for (int k = 0; k < 6; k++) {
        const int ko = k * 32;
        __syncthreads();   // previous stage fully consumed
        // ---- A: 4 arrays x 128 rows x 32 half; iter i covers 256 slots
        #pragma unroll
        for (int i = 0; i < 8; i++) {
            int a = i >> 1;
            int r = (i & 1) * 64 + rA_lo;
            int q = qsA ^ ((r >> 1) & 3);
            int node = M0 + r; node = node < N_NODES ? node : N_NODES - 1;
            dma16(gA[a] + (size_t)node * CP + ko + q * 8, smem + i * 4096 + ldso);
        }
        // ---- B: 4 arrays x 96 rows x 32 half
        #pragma unroll
        for (int i = 0; i < 6; i++) {
            int c = i * 256 + tid;
            int a = c / 384;
            int rem = c - a * 384;
            int r = rem >> 2, qs = rem & 3;
            int q = qs ^ ((r >> 1) & 3);
            dma16(gB[a] + (size_t)(N0 + r) * CP + ko + q * 8, smem + 32768 + i * 4096 + ldso);
        }
        __syncthreads();   // drains vmcnt(0): DMA data visible

        short8 xh[4], gh[4], xl[4], gl[4];
        #pragma unroll
        for (int mi = 0; mi < 4; mi++) {
            int r = wm * 64 + mi * 16 + l15;
            int sl = (r * 4 + (kb ^ ((r >> 1) & 3))) * 16;
            xh[mi] = *(const short8*)(smem + sl);
            gh[mi] = *(const short8*)(smem + 8192 + sl);
            xl[mi] = *(const short8*)(smem + 16384 + sl);
            gl[mi] = *(const short8*)(smem + 24576 + sl);
        }
        short8 fh[3], wh[3], fl[3], wl[3];
        #pragma unroll
        for (int nj = 0; nj < 3; nj++) {
            int r = wn * 48 + nj * 16 + l15;
            int sl = (r * 4 + (kb ^ ((r >> 1) & 3))) * 16;
            fh[nj] = *(const short8*)(smem + 32768 + sl);
            wh[nj] = *(const short8*)(smem + 38912 + sl);
            fl[nj] = *(const short8*)(smem + 45056 + sl);
            wl[nj] = *(const short8*)(smem + 51200 + sl);
        }
        #pragma unroll
        for (int mi = 0; mi < 4; mi++)
            #pragma unroll
            for (int nj = 0; nj < 3; nj++) {
                accGI[mi][nj] = __builtin_amdgcn_mfma_f32_16x16x32_bf16(
                    gh[mi], fh[nj], accGI[mi][nj], 0, 0, 0);
                accGI[mi][nj] = __builtin_amdgcn_mfma_f32_16x16x32_bf16(
                    gl[mi], fh[nj], accGI[mi][nj], 0, 0, 0);
                accGI[mi][nj] = __builtin_amdgcn_mfma_f32_16x16x32_bf16(
                    gh[mi], fl[nj], accGI[mi][nj], 0, 0, 0);
                accGH[mi][nj] = __builtin_amdgcn_mfma_f32_16x16x32_bf16(
                    xh[mi], wh[nj], accGH[mi][nj], 0, 0, 0);
                accGH[mi][nj] = __builtin_amdgcn_mfma_f32_16x16x32_bf16(
                    xl[mi], wh[nj], accGH[mi][nj], 0, 0, 0);
                accGH[mi][nj] = __builtin_amdgcn_mfma_f32_16x16x32_bf16(
                    xh[mi], wl[nj], accGH[mi][nj], 0, 0, 0);
            }
    }

    // ---------------- register-only GRU epilogue
    // lane channel J; acc[mi][0/1/2][reg] = gates r/z/c for (node, J)
    const int J = blockIdx.y * 32 + wn * 16 + l15;
    const bool jv = (J < CC);
    const int Je = jv ? J : 0;
    const int bo = (b * 3 + t) * THREE_C;
    const float bir = bih[bo + Je], biz = bih[bo + CC + Je], bic = bih[bo + 2 * CC + Je];
    const float bhr = bhh[bo + Je], bhz = bhh[bo + CC + Je], bhc = bhh[bo + 2 * CC + Je];
    #pragma unroll
    for (int mi = 0; mi < 4; mi++) {
        #pragma unroll
        for (int r = 0; r < 4; r++) {
            int node = M0 + wm * 64 + mi * 16 + quad * 4 + r;
            if (node < N_NODES && jv) {
                size_t xi = (size_t)(t * N_NODES + node) * CP + J;
                float xold = bf2f(XcH[xi]) + bf2f(XcL[xi]);
                float rr = 1.f / (1.f + expf(-(accGI[mi][0][r] + bir + accGH[mi][0][r] + bhr)));
                float zz = 1.f / (1.f + expf(-(accGI[mi][1][r] + biz + accGH[mi][1][r] + bhz)));
                float cg = tanhf(accGI[mi][2][r] + bic + rr * (accGH[mi][2][r] + bhc));
                float outv = (1.f - zz) * cg + zz * xold;
                unsigned short oh = f2bf(outv);
                XnH[xi] = oh;
                XnL[xi] = f2bf(outv - bf2f(oh));
            }
        }
    }
}

// --------------------------------------------------------- LayerNorm + ReLU
__global__ void k_ln(float* __restrict__ h, const unsigned short* __restrict__ XH,
                     const unsigned short* __restrict__ XL,
                     const float* __restrict__ lnw, const float* __restrict__ lnb, int b) {
    int i = blockIdx.x;
    int c = threadIdx.x;   // 192 threads
    long base = (long)i * CP + c;
    float v = 0.f;
    if (c < CC) {
        v = h[base];
        #pragma unroll
        for (int t = 0; t < NT; t++)
            v += bf2f(XH[(long)t * NC + base]) + bf2f(XL[(long)t * NC + base]);
    }
    float sv = v;
    for (int o = 32; o > 0; o >>= 1) sv += __shfl_down(sv, o);
    __shared__ float ls[3];
    __shared__ float bc[2];
    if ((threadIdx.x & 63) == 0) ls[threadIdx.x >> 6] = sv;
    __syncthreads();
    if (threadIdx.x == 0) bc[0] = (ls[0] + ls[1] + ls[2]) / (float)CC;
    __syncthreads();
    float mu = bc[0];
    float d = (c < CC) ? (v - mu) : 0.f;
    float s2 = d * d;
    for (int o = 32; o > 0; o >>= 1) s2 += __shfl_down(s2, o);
    __syncthreads();
    if ((threadIdx.x & 63) == 0) ls[threadIdx.x >> 6] = s2;
    __syncthreads();
    if (threadIdx.x == 0) bc[1] = (ls[0] + ls[1] + ls[2]) / (float)CC;
    __syncthreads();
    float var = bc[1];
    float y = 0.f;
    if (c < CC) {
        y = d * rsqrtf(var + 1e-5f) * lnw[b * CC + c] + lnb[b * CC + c];
        y = y > 0.f ? y : 0.f;
    }
    h[base] = y;
}

// --------------------------------------------------------------- pooling
__global__ void k_pool(const float* __restrict__ h, const int* __restrict__ batch,
                       float* __restrict__ hg, float* __restrict__ gcnt) {
    int idx = blockIdx.x * 256 + threadIdx.x;
    if (idx >= NC) return;
    int i = idx / CP, c = idx % CP;
    int g = batch[i];
    if (c < CC) atomicAdd(&hg[g * CP + c], h[idx]);
    if (c == 0) atomicAdd(&gcnt[g], 1.f);
}

__global__ void k_head1(const float* __restrict__ hg, const float* __restrict__ gcnt,
                        const float* __restrict__ w1, const float* __restrict__ b1,
                        float* __restrict__ z1) {
    int g = blockIdx.x;
    int jcol = threadIdx.x;
    if (jcol >= CC) return;
    float inv = 1.f / fmaxf(gcnt[g], 1.f);
    float acc = 0.f;
    for (int k = 0; k < CC; k++) acc += hg[g * CP + k] * inv * w1[k * CC + jcol];
    acc += b1[jcol];
    z1[g * CP + jcol] = fmaxf(acc, 0.f);
}

__global__ void k_head2(const float* __restrict__ z1, const float* __restrict__ w2,
                        const float* __restrict__ b2, float* __restrict__ out) {
    int idx = threadIdx.x;
    if (idx >= GG * 2) return;
    int g = idx / 2, o = idx % 2;
    float acc = 0.f;
    for (int k = 0; k < CC; k++) acc += z1[g * CP + k] * w2[k * 2 + o];
    out[g * 2 + o] = acc + b2[o];
}

// ================================================================ launch
extern "C" void kernel_launch(void* const* d_in, const int* in_sizes, int n_in,
                              void* d_out, int out_size, void* d_ws, size_t ws_size,
                              hipStream_t stream) {
    const float* xs   = (const float*)d_in[0];
    const float* conv = (const float*)d_in[1];
    const float* wih  = (const float*)d_in[2];
    const float* whh  = (const float*)d_in[3];
    const float* bih  = (const float*)d_in[4];
    const float* bhh  = (const float*)d_in[5];
    const float* lnw  = (const float*)d_in[6];
    const float* lnb  = (const float*)d_in[7];
    const float* hw1  = (const float*)d_in[8];
    const float* hb1  = (const float*)d_in[9];
    const float* hw2  = (const float*)d_in[10];
    const float* hb2  = (const float*)d_in[11];
    const int* xtype  = (const int*)d_in[12];
    const int* xtok   = (const int*)d_in[13];
    const int* ei     = (const int*)d_in[14];
    const int* et     = (const int*)d_in[15];
    const int* batch  = (const int*)d_in[16];
    float* out = (float*)d_out;

    char* ws = (char*)d_ws;
    size_t o = 0;
    auto alloc = [&](size_t nbytes) {
        size_t r = o;
        o = (o + nbytes + 255) & ~(size_t)255;
        return r;
    };
    float* h      = (float*)(ws + alloc((size_t)NC * 4));
    float* F_t    = (float*)(ws + alloc((size_t)30 * THREE_C * CP * 4));
    float* wih_p  = (float*)(ws + alloc((size_t)15 * THREE_C * CP * 4));
    float* whh_p  = (float*)(ws + alloc((size_t)15 * THREE_C * CP * 4));
    float* convp  = (float*)(ws + alloc((size_t)150 * 192 * 192 * 4));
    unsigned short* FH  = (unsigned short*)(ws + alloc((size_t)30 * NPAD * CP * 2));
    unsigned short* FL  = (unsigned short*)(ws + alloc((size_t)30 * NPAD * CP * 2));
    unsigned short* WH  = (unsigned short*)(ws + alloc((size_t)3 * NPAD * CP * 2));
    unsigned short* WL  = (unsigned short*)(ws + alloc((size_t)3 * NPAD * CP * 2));
    unsigned short* XAh = (unsigned short*)(ws + alloc((size_t)NT * NC * 2));
    unsigned short* XAl = (unsigned short*)(ws + alloc((size_t)NT * NC * 2));
    unsigned short* XBh = (unsigned short*)(ws + alloc((size_t)NT * NC * 2));
    unsigned short* XBl = (unsigned short*)(ws + alloc((size_t)NT * NC * 2));
    unsigned short* AggH = (unsigned short*)(ws + alloc((size_t)NT * NC * 2));
    unsigned short* AggL = (unsigned short*)(ws + alloc((size_t)NT * NC * 2));
    float* hg     = (float*)(ws + alloc((size_t)GG * CP * 4));
    float* gcnt   = (float*)(ws + alloc((size_t)GG * 4));
    float* z1buf  = (float*)(ws + alloc((size_t)GG * CP * 4));
    int* cnt      = (int*)(ws + alloc((size_t)NT * N_NODES * 4));
    int* offb     = (int*)(ws + alloc((size_t)(NT * N_NODES + 1) * 4));
    int* fillb    = (int*)(ws + alloc((size_t)NT * N_NODES * 4));
    int* csrc     = (int*)(ws + alloc((size_t)EE * 4));
    (void)ws_size; (void)n_in; (void)in_sizes; (void)out_size;

    hipMemsetAsync(cnt, 0, (size_t)NT * N_NODES * 4, stream);
    hipMemsetAsync(hg, 0, (size_t)GG * CP * 4, stream);
    hipMemsetAsync(gcnt, 0, (size_t)GG * 4, stream);

    k_build_h<<<(NC + 255) / 256, 256, 0, stream>>>(xs, xtype, xtok, h);
    k_pad_conv<<<(int)((150L * 192 * 192 + 255) / 256), 256, 0, stream>>>(conv, convp);
    k_pad573<<<(int)(((long)15 * THREE_C * CP + 255) / 256), 256, 0, stream>>>(wih, wih_p, 15);
    k_pad573<<<(int)(((long)15 * THREE_C * CP + 255) / 256), 256, 0, stream>>>(whh, whh_p, 15);
    k_edge_count<<<(EE + 255) / 256, 256, 0, stream>>>(ei, et, cnt);
    k_scan<<<1, 256, 0, stream>>>(cnt, offb, fillb);
    k_edge_fill<<<(EE + 255) / 256, 256, 0, stream>>>(ei, et, fillb, csrc);

    for (int b = 0; b < NB; b++) {
        dim3 fg((THREE_C + 31) / 32, 3, 30);
        k_fmat<<<fg, 256, 0, stream>>>(wih_p, convp, F_t, b);
        k_convF<<<(int)((30L * NPAD * CP + 255) / 256), 256, 0, stream>>>(F_t, FH, FL);
        k_convW<<<(int)((3L * NPAD * CP + 255) / 256), 256, 0, stream>>>(whh_p, WH, WL, b);
        k_split3<<<(NC + 255) / 256, 256, 0, stream>>>(h, XAh, XAl);
        unsigned short *curH = XAh, *curL = XAl, *nxtH = XBh, *nxtL = XBl;
        for (int s = 0; s < NS; s++) {
            k_agg<<<dim3(N_NODES, NT), CP, 0, stream>>>(curH, curL, AggH, AggL, offb, csrc);
            dim3 sg(32, 6, NT);   // 4096/128 node tiles x 576/96 gate tiles x types
            k_step<<<sg, 256, 0, stream>>>(curH, curL, AggH, AggL, FH, FL, WH, WL,
                                           bih, bhh, nxtH, nxtL, b, s);
            unsigned short* t1 = curH; curH = nxtH; nxtH = t1;
            unsigned short* t2 = curL; curL = nxtL; nxtL = t2;
        }
        // NS even -> final state is back in XAh/XAl
        k_ln<<<N_NODES, CP, 0, stream>>>(h, XAh, XAl, lnw, lnb, b);
    }

    k_pool<<<(NC + 255) / 256, 256, 0, stream>>>(h, batch, hg, gcnt);
    k_head1<<<GG, CP, 0, stream>>>(hg, gcnt, hw1, hb1, z1buf);
    k_head2<<<1, 64, 0, stream>>>(z1buf, hw2, hb2, out);
}